// Round 1
// baseline (1368.457 us; speedup 1.0000x reference)
//
#include <hip/hip_runtime.h>

// Problem constants
#define NB    64      // batch
#define LCAP  51      // caption length
#define TT    50      // decode steps
#define HID   512
#define EMB   512
#define VOC   30000
#define ENCD  2048
#define G4    2048    // 4*HID

typedef unsigned short u16;
typedef __attribute__((ext_vector_type(8))) short bf16x8;
typedef __attribute__((ext_vector_type(4))) float f32x4;

__device__ __forceinline__ u16 f2bf(float x) {
  union { float f; unsigned u; } v; v.f = x;
  unsigned r = v.u + 0x7fffu + ((v.u >> 16) & 1u);
  return (u16)(r >> 16);
}

// ---------------- sort + int outputs ----------------
// stable argsort of -lengths: rank_i = #{j: len_j>len_i or (len_j==len_i and j<i)}
__global__ __launch_bounds__(64) void sort_k(const int* __restrict__ cap_len,
                                             const int* __restrict__ caps,
                                             float* __restrict__ out,
                                             int* __restrict__ sind,
                                             int* __restrict__ dlen) {
  __shared__ int smlen[NB];
  __shared__ int smpos[NB];
  int i = threadIdx.x;
  smlen[i] = cap_len[i];
  __syncthreads();
  int li = smlen[i];
  int rank = 0;
  for (int j = 0; j < NB; ++j) {
    int lj = smlen[j];
    rank += (lj > li || (lj == li && j < i)) ? 1 : 0;
  }
  smpos[rank] = i;
  __syncthreads();
  int src = smpos[i];                 // sorted position i <- original index src
  int dl = smlen[src] - 1;
  sind[i] = src;
  dlen[i] = dl;
  float* caps_out = out + (size_t)NB * TT * VOC;          // 96,000,000
  for (int l = 0; l < LCAP; ++l)
    caps_out[i * LCAP + l] = (float)caps[src * LCAP + l];
  out[96003264 + i] = (float)dl;       // dec_len
  out[96003328 + i] = (float)src;      // sort_ind
}

// ---------------- converts / gathers ----------------
__global__ __launch_bounds__(256) void conv4(const float* __restrict__ src,
                                             u16* __restrict__ dst, int n4) {
  int i = blockIdx.x * 256 + threadIdx.x;
  if (i >= n4) return;
  float4 v = ((const float4*)src)[i];
  ushort4 o;
  o.x = f2bf(v.x); o.y = f2bf(v.y); o.z = f2bf(v.z); o.w = f2bf(v.w);
  ((ushort4*)dst)[i] = o;
}

// Winit = concat(w_init_h, w_init_c) rows -> [1024][2048] bf16
__global__ __launch_bounds__(256) void conv_winit_k(const float* __restrict__ wh,
                                                    const float* __restrict__ wc,
                                                    u16* __restrict__ dst) {
  int i = blockIdx.x * 256 + threadIdx.x;   // i over 2097152/4
  if (i >= 524288) return;
  int e = i * 4;
  int row = e >> 11;           // /2048
  int col = e & 2047;
  const float* src = (row < 512) ? (wh + (size_t)row * 2048 + col)
                                 : (wc + (size_t)(row - 512) * 2048 + col);
  float4 v = *(const float4*)src;
  ushort4 o;
  o.x = f2bf(v.x); o.y = f2bf(v.y); o.z = f2bf(v.z); o.w = f2bf(v.w);
  ((ushort4*)dst)[i] = o;
}

// enc_bf[r][k] = bf16(encoder_out[sind[r]][k])
__global__ __launch_bounds__(256) void gather_enc_k(const float* __restrict__ enc,
                                                    const int* __restrict__ sind,
                                                    u16* __restrict__ dst) {
  int i = blockIdx.x * 256 + threadIdx.x;   // over 64*2048/4
  if (i >= 32768) return;
  int e = i * 4;
  int r = e >> 11;
  int k = e & 2047;
  float4 v = *(const float4*)(enc + (size_t)sind[r] * ENCD + k);
  ushort4 o;
  o.x = f2bf(v.x); o.y = f2bf(v.y); o.z = f2bf(v.z); o.w = f2bf(v.w);
  ((ushort4*)dst)[i] = o;
}

// Xb[(b*50+t)][k] = bf16(emb[caps[sind[b]*51 + t]][k])
__global__ __launch_bounds__(256) void gather_x_k(const float* __restrict__ emb,
                                                  const int* __restrict__ caps,
                                                  const int* __restrict__ sind,
                                                  u16* __restrict__ dst) {
  int i = blockIdx.x * 256 + threadIdx.x;   // over 3200*512/4
  if (i >= 409600) return;
  int e = i * 4;
  int m = e >> 9;              // /512
  int k = e & 511;
  unsigned b = ((unsigned)m * 5243u) >> 18;   // m/50, valid for m < 43690
  int t = m - (int)b * TT;
  int cap = caps[sind[b] * LCAP + t];
  float4 v = *(const float4*)(emb + (size_t)cap * EMB + k);
  ushort4 o;
  o.x = f2bf(v.x); o.y = f2bf(v.y); o.z = f2bf(v.z); o.w = f2bf(v.w);
  ((ushort4*)dst)[i] = o;
}

// ---------------- bf16 MFMA GEMM: C[M][N] = A[M][K] * B[N][K]^T ----------------
// EPI 0: xW   -> out0[row*Nr+col] = acc + bias0[col] + bias1[col]
// EPI 1: init -> col<512: out0 (h0) + bias0; else out1 (c0) + bias1
// EPI 2: fc   -> masked preds + b_fc; fully-masked tiles fast-path zeros
#define BM 128
#define BN 128
#define BK 32
#define LDT 40    // LDS row stride (bf16 elems); 80B = 20 dwords -> 2-way max

template <int EPI>
__global__ __launch_bounds__(256) void gemm_bt(const u16* __restrict__ A,
                                               const u16* __restrict__ Bm,
                                               int Mr, int Nr, int K,
                                               float* __restrict__ out0,
                                               float* __restrict__ out1,
                                               const float* __restrict__ bias0,
                                               const float* __restrict__ bias1,
                                               const int* __restrict__ dlen) {
  __shared__ u16 As[BM * LDT];
  __shared__ u16 Bs[BN * LDT];
  int tid = threadIdx.x;
  int mBase = blockIdx.y * BM;
  int nBase = blockIdx.x * BN;

  if (EPI == 2) {
    // skip K-loop if every row in this tile is masked
    __shared__ int any_active;
    if (tid == 0) any_active = 0;
    __syncthreads();
    if (tid < BM) {
      int row = mBase + tid;
      unsigned b = ((unsigned)row * 5243u) >> 18;
      int t = row - (int)b * TT;
      if (t < dlen[b]) any_active = 1;
    }
    __syncthreads();
    if (!any_active) {
      for (int i = tid; i < BM * BN; i += 256) {
        int r = i >> 7, cc = i & 127;
        int col = nBase + cc;
        if (col < Nr) out0[(size_t)(mBase + r) * Nr + col] = 0.f;
      }
      return;
    }
  }

  int wid = tid >> 6, lane = tid & 63;
  int wm = (wid >> 1) * 64, wn = (wid & 1) * 64;
  int lm = lane & 15, lq = lane >> 4;

  f32x4 acc[4][4];
  for (int i = 0; i < 4; ++i)
    for (int j = 0; j < 4; ++j)
      acc[i][j] = (f32x4){0.f, 0.f, 0.f, 0.f};

  int nkt = K / BK;
  for (int kt = 0; kt < nkt; ++kt) {
    for (int it = 0; it < 2; ++it) {
      int li = tid + it * 256;       // 0..511
      int row = li >> 2, kq = li & 3;
      {
        int gr = min(mBase + row, Mr - 1);
        uint4 v = *(const uint4*)(A + (size_t)gr * K + kt * BK + kq * 8);
        *(uint4*)&As[row * LDT + kq * 8] = v;
      }
      {
        int gr = min(nBase + row, Nr - 1);
        uint4 v = *(const uint4*)(Bm + (size_t)gr * K + kt * BK + kq * 8);
        *(uint4*)&Bs[row * LDT + kq * 8] = v;
      }
    }
    __syncthreads();
    bf16x8 af[4], bfr[4];
    for (int i = 0; i < 4; ++i)
      af[i] = *(const bf16x8*)&As[(wm + i * 16 + lm) * LDT + lq * 8];
    for (int j = 0; j < 4; ++j)
      bfr[j] = *(const bf16x8*)&Bs[(wn + j * 16 + lm) * LDT + lq * 8];
    for (int i = 0; i < 4; ++i)
      for (int j = 0; j < 4; ++j)
        acc[i][j] = __builtin_amdgcn_mfma_f32_16x16x32_bf16(af[i], bfr[j], acc[i][j], 0, 0, 0);
    __syncthreads();
  }

  // epilogue: C row = (lane>>4)*4 + reg, col = lane&15  (verified m89/m91 layout)
  for (int i = 0; i < 4; ++i) {
    int row0 = mBase + wm + i * 16 + (lane >> 4) * 4;
    for (int j = 0; j < 4; ++j) {
      int col = nBase + wn + j * 16 + (lane & 15);
      for (int r = 0; r < 4; ++r) {
        int row = row0 + r;
        float v = acc[i][j][r];
        if (EPI == 0) {
          if (row < Mr && col < Nr)
            out0[(size_t)row * Nr + col] = v + bias0[col] + bias1[col];
        } else if (EPI == 1) {
          if (row < Mr && col < Nr) {
            if (col < 512) out0[(size_t)row * 512 + col] = v + bias0[col];
            else           out1[(size_t)row * 512 + (col - 512)] = v + bias1[col - 512];
          }
        } else {
          if (col < Nr) {
            unsigned b = ((unsigned)row * 5243u) >> 18;
            int t = row - (int)b * TT;
            float o = (t < dlen[b]) ? (v + bias0[col]) : 0.f;
            out0[(size_t)row * Nr + col] = o;
          }
        }
      }
    }
  }
}

// ---------------- LSTM step (fused gates-from-h + pointwise) ----------------
// grid 256: blockIdx = bg(0..3: 16-batch group) + 4*ug(0..63: 8-unit group)
// thread: b = tid&15, u_idx = (tid>>4)&7, gp = tid>>7 (gates {0,1} or {2,3})
__global__ __launch_bounds__(256) void lstm_step(const float* __restrict__ h_in,
                                                 float* __restrict__ h_out,
                                                 float* __restrict__ c,
                                                 const float* __restrict__ xW,
                                                 const float* __restrict__ w_hh,
                                                 u16* __restrict__ Hs,
                                                 int t) {
  __shared__ float hsm[16 * 512];
  __shared__ float exch[8][16][4];
  int tid = threadIdx.x;
  int bg = blockIdx.x & 3;
  int ug = blockIdx.x >> 2;

  // stage 16 h rows, coalesced
  const float4* hsrc = (const float4*)(h_in + (size_t)bg * 16 * HID);
  for (int i = tid; i < 16 * 512 / 4; i += 256)
    ((float4*)hsm)[i] = hsrc[i];
  __syncthreads();

  int b = tid & 15;
  int u_idx = (tid >> 4) & 7;
  int gp = tid >> 7;
  int u = ug * 8 + u_idx;
  int g0 = gp * 2;
  const float* w0 = w_hh + (size_t)(g0 * HID + u) * HID;
  const float* w1 = w_hh + (size_t)((g0 + 1) * HID + u) * HID;

  float d0 = 0.f, d1 = 0.f;
  int k0 = 4 * b;   // lane rotation: LDS banks (5b+s), aligned float4
#pragma unroll 8
  for (int s = 0; s < 128; ++s) {
    int k = (k0 + 4 * s) & 511;
    float4 hv = *(const float4*)&hsm[b * 512 + k];
    float4 w0v = *(const float4*)&w0[k];
    float4 w1v = *(const float4*)&w1[k];
    d0 += hv.x * w0v.x + hv.y * w0v.y + hv.z * w0v.z + hv.w * w0v.w;
    d1 += hv.x * w1v.x + hv.y * w1v.y + hv.z * w1v.z + hv.w * w1v.w;
  }
  exch[u_idx][b][g0] = d0;
  exch[u_idx][b][g0 + 1] = d1;
  __syncthreads();

  if (tid < 128) {
    int b2 = tid & 15, u2 = tid >> 4;
    int bglob = bg * 16 + b2;
    int uu = ug * 8 + u2;
    int m = bglob * TT + t;
    const float* xw = xW + (size_t)m * G4;
    float gi = exch[u2][b2][0] + xw[uu];
    float gf = exch[u2][b2][1] + xw[512 + uu];
    float gg = exch[u2][b2][2] + xw[1024 + uu];
    float go = exch[u2][b2][3] + xw[1536 + uu];
    float si = 1.f / (1.f + expf(-gi));
    float sf = 1.f / (1.f + expf(-gf));
    float so = 1.f / (1.f + expf(-go));
    float tg = tanhf(gg);
    size_t ci = (size_t)bglob * HID + uu;
    float cn = sf * c[ci] + si * tg;
    c[ci] = cn;
    float hn = so * tanhf(cn);
    h_out[ci] = hn;
    Hs[(size_t)m * HID + uu] = f2bf(hn);
  }
}

// ---------------- launcher ----------------
extern "C" void kernel_launch(void* const* d_in, const int* in_sizes, int n_in,
                              void* d_out, int out_size, void* d_ws, size_t ws_size,
                              hipStream_t stream) {
  const float* encoder_out = (const float*)d_in[0];
  const int*   caps        = (const int*)d_in[1];
  const int*   cap_len     = (const int*)d_in[2];
  const float* emb         = (const float*)d_in[3];
  const float* w_ih        = (const float*)d_in[4];
  const float* b_ih        = (const float*)d_in[5];
  const float* w_hh        = (const float*)d_in[6];
  const float* b_hh        = (const float*)d_in[7];
  const float* w_init_h    = (const float*)d_in[8];
  const float* b_init_h    = (const float*)d_in[9];
  const float* w_init_c    = (const float*)d_in[10];
  const float* b_init_c    = (const float*)d_in[11];
  const float* w_fc        = (const float*)d_in[12];
  const float* b_fc        = (const float*)d_in[13];
  float* out = (float*)d_out;

  char* ws = (char*)d_ws;          // ~70.4 MB used
  int*   sind  = (int*)(ws + 0);
  int*   dlen  = (int*)(ws + 256);
  float* hA    = (float*)(ws + 512);
  float* hB    = (float*)(ws + 131584);
  float* cbuf  = (float*)(ws + 262656);
  float* xW    = (float*)(ws + 393728);
  u16*   Hs    = (u16*)(ws + 26608128);
  u16*   Xb    = (u16*)(ws + 29884928);
  u16*   Wih   = (u16*)(ws + 33161728);
  u16*   Winit = (u16*)(ws + 35258880);
  u16*   Wfc   = (u16*)(ws + 39453184);
  u16*   Ebf   = (u16*)(ws + 70173184);

  sort_k<<<1, 64, 0, stream>>>(cap_len, caps, out, sind, dlen);
  conv4<<<1024, 256, 0, stream>>>(w_ih, Wih, 262144);
  conv_winit_k<<<2048, 256, 0, stream>>>(w_init_h, w_init_c, Winit);
  conv4<<<15000, 256, 0, stream>>>(w_fc, Wfc, 3840000);
  gather_enc_k<<<128, 256, 0, stream>>>(encoder_out, sind, Ebf);
  gather_x_k<<<1600, 256, 0, stream>>>(emb, caps, sind, Xb);

  // h0 | c0
  gemm_bt<1><<<dim3(8, 1), 256, 0, stream>>>(Ebf, Winit, 64, 1024, 2048,
                                             hA, cbuf, b_init_h, b_init_c, nullptr);
  // xW = X @ w_ih^T + b_ih + b_hh  (all steps at once)
  gemm_bt<0><<<dim3(16, 25), 256, 0, stream>>>(Xb, Wih, 3200, 2048, 512,
                                               xW, nullptr, b_ih, b_hh, nullptr);
  // 50 sequential LSTM steps (h ping-pong, c in place)
  for (int t = 0; t < TT; ++t) {
    const float* hin = (t & 1) ? hB : hA;
    float* hout = (t & 1) ? hA : hB;
    lstm_step<<<256, 256, 0, stream>>>(hin, hout, cbuf, xW, w_hh, Hs, t);
  }
  // predictions = Hs @ w_fc^T + b_fc, masked
  gemm_bt<2><<<dim3(235, 25), 256, 0, stream>>>(Hs, Wfc, 3200, VOC, 512,
                                                out, nullptr, b_fc, nullptr, dlen);
}